// Round 1
// baseline (141.963 us; speedup 1.0000x reference)
//
#include <hip/hip_runtime.h>

// MendGraph: pure data-movement kernel.
// Output layout (flat float32, out_size = (N + N*P)*D + 2*(E + 2*N*P)):
//   [0, N*D)                      : x copied
//   [N*D, (N+N*P)*D)              : predicted_features copied
//   [OUT_X, OUT_X + E)            : edges row0 (int -> float)
//   [OUT_X + E, OUT_X + E_out)    : generated e0 per node: [i x P, base+P*i+0..P-1]
//   [OUT_X + E_out, ... + E)      : edges row1
//   [... + E, ... + E_out)        : generated e1 per node: [base+P*i+0..P-1, i x P]
// where OUT_X = (N + N*P)*D, E_out = E + 2*N*P, base = N.

__global__ void mendgraph_copy4(const float4* __restrict__ x4,
                                const float4* __restrict__ pred4,
                                const int4*  __restrict__ edges4,
                                float* __restrict__ out,
                                long n4_x, long n4_p, long n4_e_row,
                                long e4_row_src,   // E/4 (source row stride in int4)
                                long E_out,        // output row length (elements)
                                long out_x_elems)  // OUT_X
{
    const long total = n4_x + n4_p + 2 * n4_e_row;
    const long stride = (long)gridDim.x * blockDim.x;
    float4* __restrict__ out4 = reinterpret_cast<float4*>(out);

    for (long t = (long)blockIdx.x * blockDim.x + threadIdx.x; t < total; t += stride) {
        if (t < n4_x) {
            out4[t] = x4[t];
        } else if (t < n4_x + n4_p) {
            out4[t] = pred4[t - n4_x];
        } else {
            long u   = t - n4_x - n4_p;
            long row = (u >= n4_e_row) ? 1 : 0;
            long j4  = u - row * n4_e_row;
            int4 v   = edges4[row * e4_row_src + j4];
            float4 f = make_float4((float)v.x, (float)v.y, (float)v.z, (float)v.w);
            *reinterpret_cast<float4*>(out + out_x_elems + row * E_out + j4 * 4) = f;
        }
    }
}

__global__ void mendgraph_newedges(float* __restrict__ out,
                                   long out_x_elems, long E, long E_out,
                                   int N, int P)
{
    const long per_row = (long)N * 2 * P;       // entries appended per edge row
    const long total   = 2 * per_row;
    const long stride  = (long)gridDim.x * blockDim.x;
    const int  twoP    = 2 * P;

    for (long idx = (long)blockIdx.x * blockDim.x + threadIdx.x; idx < total; idx += stride) {
        long row = (idx >= per_row) ? 1 : 0;
        long r   = idx - row * per_row;
        int  i   = (int)(r / twoP);
        int  k   = (int)(r - (long)i * twoP);
        int  val;
        if (row == 0) val = (k < P) ? i : (N + i * P + (k - P));
        else          val = (k < P) ? (N + i * P + k) : i;
        out[out_x_elems + row * E_out + E + r] = (float)val;
    }
}

extern "C" void kernel_launch(void* const* d_in, const int* in_sizes, int n_in,
                              void* d_out, int out_size, void* d_ws, size_t ws_size,
                              hipStream_t stream) {
    const float* x     = (const float*)d_in[0];
    const int*   edges = (const int*)d_in[1];
    const float* preds = (const float*)d_in[2];
    // d_in[3] = node_ids (arange); only N is needed.

    const long N = in_sizes[3];
    const long D = in_sizes[0] / N;               // 128
    const long P = in_sizes[2] / (N * D);         // 5
    const long E = in_sizes[1] / 2;               // 3,200,000

    const long E_out       = E + 2 * N * P;       // 4,200,000
    const long out_x_elems = (N + N * P) * D;     // 76,800,000

    const long n4_x    = (N * D) / 4;             // 3.2M
    const long n4_p    = (N * P * D) / 4;         // 16M
    const long n4_e    = E / 4;                   // 800K per row

    {
        const int block = 256;
        const long total4 = n4_x + n4_p + 2 * n4_e;
        long blocks = (total4 + block - 1) / block;
        if (blocks > 4096) blocks = 4096;
        mendgraph_copy4<<<(int)blocks, block, 0, stream>>>(
            (const float4*)x, (const float4*)preds, (const int4*)edges,
            (float*)d_out, n4_x, n4_p, n4_e, E / 4, E_out, out_x_elems);
    }
    {
        const int block = 256;
        const long total = 2L * N * 2 * P;        // 2,000,000
        long blocks = (total + block - 1) / block;
        if (blocks > 4096) blocks = 4096;
        mendgraph_newedges<<<(int)blocks, block, 0, stream>>>(
            (float*)d_out, out_x_elems, E, E_out, (int)N, (int)P);
    }
}

// Round 3
// 123.382 us; speedup vs baseline: 1.1506x; 1.1506x over previous
//
#include <hip/hip_runtime.h>

// MendGraph: pure data movement.
// Output (flat float32): [x | preds] then edges row0 [orig | generated] then row1.
//   OUT_X = (N + N*P)*D elements; E_out = E + 2*N*P elements per edge row.
// All segment boundaries divisible by 4 for the production shape
// (N=100000, P=5, D=128, E=3200000), so vec4 addressing is exact.

typedef float f32x4 __attribute__((ext_vector_type(4)));
typedef int   i32x4 __attribute__((ext_vector_type(4)));

__global__ __launch_bounds__(256) void mendgraph_fused(
    const f32x4* __restrict__ x4,
    const f32x4* __restrict__ pred4,
    const i32x4* __restrict__ edges4,
    f32x4* __restrict__ out4,
    long n4_x,      // N*D/4
    long n4_p,      // N*P*D/4
    long n4_e,      // E/4
    long n4_new,    // N*2*P/4
    long out_x4,    // OUT_X/4
    long E_out4,    // E_out/4
    int N, int P)
{
    const long S = (long)gridDim.x * blockDim.x;
    const long g = (long)blockIdx.x * blockDim.x + threadIdx.x;
    const int twoP = 2 * P;

    // 1) x -> out[0, N*D)
    for (long t = g; t < n4_x; t += S) {
        f32x4 v = __builtin_nontemporal_load(x4 + t);
        __builtin_nontemporal_store(v, out4 + t);
    }

    // 2) predicted_features -> out[N*D, (N+N*P)*D)
    for (long t = g; t < n4_p; t += S) {
        f32x4 v = __builtin_nontemporal_load(pred4 + t);
        __builtin_nontemporal_store(v, out4 + n4_x + t);
    }

    // 3) original edges, both rows: int -> float convert-copy
    #pragma unroll
    for (int row = 0; row < 2; ++row) {
        const i32x4* src = edges4 + (long)row * n4_e;
        f32x4*       dst = out4 + out_x4 + (long)row * E_out4;
        for (long t = g; t < n4_e; t += S) {
            i32x4 v = __builtin_nontemporal_load(src + t);
            f32x4 f;
            f.x = (float)v.x; f.y = (float)v.y; f.z = (float)v.z; f.w = (float)v.w;
            __builtin_nontemporal_store(f, dst + t);
        }
    }

    // 4) generated new-edge ids, both rows.
    //    element e: i = e/(2P), k = e%(2P)
    //    row0 val = k<P ? i : N + i*P + (k-P);  row1 val = k<P ? N + i*P + k : i
    #pragma unroll
    for (int row = 0; row < 2; ++row) {
        f32x4* dst = out4 + out_x4 + (long)row * E_out4 + n4_e;
        for (long t = g; t < n4_new; t += S) {
            long e = 4 * t;
            f32x4 f;
            #pragma unroll
            for (int q = 0; q < 4; ++q) {
                long ee = e + q;
                int i = (int)(ee / twoP);
                int k = (int)(ee - (long)i * twoP);
                int val;
                if (row == 0) val = (k < P) ? i : (N + i * P + (k - P));
                else          val = (k < P) ? (N + i * P + k) : i;
                f[q] = (float)val;
            }
            __builtin_nontemporal_store(f, dst + t);
        }
    }
}

extern "C" void kernel_launch(void* const* d_in, const int* in_sizes, int n_in,
                              void* d_out, int out_size, void* d_ws, size_t ws_size,
                              hipStream_t stream) {
    const float* x     = (const float*)d_in[0];
    const int*   edges = (const int*)d_in[1];
    const float* preds = (const float*)d_in[2];
    // d_in[3] = node_ids (arange); only N is needed.

    const long N = in_sizes[3];
    const long D = in_sizes[0] / N;               // 128
    const long P = in_sizes[2] / (N * D);         // 5
    const long E = in_sizes[1] / 2;               // 3,200,000

    const long E_out       = E + 2 * N * P;       // 4,200,000
    const long out_x_elems = (N + N * P) * D;     // 76,800,000

    const long n4_x   = (N * D) / 4;              // 3.2M
    const long n4_p   = (N * P * D) / 4;          // 16M
    const long n4_e   = E / 4;                    // 800K per row
    const long n4_new = (N * 2 * P) / 4;          // 250K per row

    const int block = 256;
    const long total4 = n4_x + n4_p + 2 * (n4_e + n4_new);
    long blocks = (total4 + block - 1) / block;
    if (blocks > 4096) blocks = 4096;

    mendgraph_fused<<<(int)blocks, block, 0, stream>>>(
        (const f32x4*)x, (const f32x4*)preds, (const i32x4*)edges,
        (f32x4*)d_out, n4_x, n4_p, n4_e, n4_new,
        out_x_elems / 4, E_out / 4, (int)N, (int)P);
}